// Round 5
// baseline (378.387 us; speedup 1.0000x reference)
//
#include <hip/hip_runtime.h>
#include <hip/hip_bf16.h>

typedef __bf16 bf16_t;
typedef __attribute__((ext_vector_type(8))) __bf16 bf16x8;
typedef __attribute__((ext_vector_type(4))) __bf16 bf16x4;
typedef __attribute__((ext_vector_type(4))) float floatx4;

#define NB 8192   // rows of x (B)
#define NC 8192   // rows of y (C)
#define ND 256    // feature dim D
#define BM 128
#define BN 128
#define LOG2E 1.44269504088896340736f

// ---------------------------------------------------------------------------
// prep: fp32 -> bf16 copies of x and y, plus SCALED row squared-norms:
//   x2s[r] = gamma * log2(e) * ||x_r||^2   (same for y2s)
// One wave per row (256 floats = 64 lanes x float4).
// ---------------------------------------------------------------------------
__global__ __launch_bounds__(256) void prep_kernel(
    const float* __restrict__ x, const float* __restrict__ y,
    const float* __restrict__ gamma_p,
    bf16_t* __restrict__ xb, bf16_t* __restrict__ yb,
    float* __restrict__ x2s, float* __restrict__ y2s)
{
    int t    = threadIdx.x;
    int wave = t >> 6;
    int lane = t & 63;
    int row  = blockIdx.x * 4 + wave;   // 0..16383 (x rows then y rows)

    const float* src;
    bf16_t* dst;
    float* nrm;
    int r;
    if (row < NB) { src = x; dst = xb; nrm = x2s; r = row; }
    else          { src = y; dst = yb; nrm = y2s; r = row - NB; }

    float4 v = ((const float4*)(src + (size_t)r * ND))[lane];
    float ss = v.x * v.x + v.y * v.y + v.z * v.z + v.w * v.w;

    bf16x4 o;
    o.x = (__bf16)v.x; o.y = (__bf16)v.y; o.z = (__bf16)v.z; o.w = (__bf16)v.w;
    ((bf16x4*)(dst + (size_t)r * ND))[lane] = o;

    #pragma unroll
    for (int off = 32; off >= 1; off >>= 1)
        ss += __shfl_xor(ss, off, 64);
    if (lane == 0) nrm[r] = ss * (LOG2E * gamma_p[0]);
}

// ---------------------------------------------------------------------------
// RBF GEMM, LDS-FREE: out[b,c] = 2^( min( A2*dot(x_b,y_c) - (x2s+y2s), 0 ) ).
// xb+yb = 8 MB total and is L2/L3-resident (FETCH_SIZE ~ 0 across rounds), so
// LDS staging of cache-fitting data was pure overhead (Common-mistake #7).
// Each wave loads its MFMA fragments DIRECTLY from L2:
//   per fragment-load instr the wave covers 16 rows x 64 B contiguous
//   (quad*16 spans the 64-B line) -> every fetched line fully used.
// Fully unrolled K (4 kt x 2 kk): 64 global_load_dwordx4 with compile-time
// immediate offsets (max 448 < 4095), 128 MFMA, ZERO barriers / LDS / sync.
// 2D XCD swizzle: per-XCD working set 2MB(x)+1MB(y) = 3MB < 4MB L2.
// __launch_bounds__(256,3): ~170 VGPR cap (acc 64 + 8 base ptrs 16 + frag
// pipeline) -> 12 waves/CU to hide ~200cy L2 latency.
// ---------------------------------------------------------------------------
__global__ __launch_bounds__(256, 3) void rbf_gemm_kernel(
    const bf16_t* __restrict__ xb, const bf16_t* __restrict__ yb,
    const float* __restrict__ x2s, const float* __restrict__ y2s,
    const float* __restrict__ gamma_p, float* __restrict__ out)
{
    const int t    = threadIdx.x;
    const int lane = t & 63;
    const int wave = t >> 6;
    const int wm   = wave >> 1;      // 2x2 wave grid over the 128x128 tile
    const int wn   = wave & 1;
    const int quad = lane >> 4;
    const int l15  = lane & 15;

    // --- XCD-aware 2D tile swizzle (blockIdx.x fastest; n%8 = XCD) ---
    const unsigned n   = blockIdx.y * 64u + blockIdx.x;
    const unsigned xcd = n & 7u;
    const unsigned s   = n >> 3;            // 0..511 within XCD
    const unsigned tbm = (xcd & 1u) * 32u + (s & 31u);   // M-tile 0..63
    const unsigned tbn = (xcd >> 1) * 16u + (s >> 5);    // N-tile 0..63

    const int bm = (int)tbm * BM;
    const int bn = (int)tbn * BN;

    const float A2 = 2.0f * LOG2E * gamma_p[0];

    // Per-lane fragment base pointers. Row stride in bf16 array = 512 B.
    // A-frag i: row bm+wm*64+i*16+l15, byte col quad*16 (+ kt*128 + kk*64).
    const char* abase[4];
    const char* bbase[4];
    #pragma unroll
    for (int i = 0; i < 4; ++i) {
        abase[i] = (const char*)xb
                 + (size_t)(bm + wm * 64 + i * 16 + l15) * (ND * 2) + quad * 16;
        bbase[i] = (const char*)yb
                 + (size_t)(bn + wn * 64 + i * 16 + l15) * (ND * 2) + quad * 16;
    }

    floatx4 acc[4][4];
    #pragma unroll
    for (int i = 0; i < 4; ++i)
        #pragma unroll
        for (int j = 0; j < 4; ++j)
            acc[i][j] = (floatx4){0.f, 0.f, 0.f, 0.f};

    #pragma unroll
    for (int kt = 0; kt < 4; ++kt) {
        #pragma unroll
        for (int kk = 0; kk < 2; ++kk) {
            const int off = kt * 128 + kk * 64;      // compile-time immediate
            bf16x8 af[4], bfr[4];
            #pragma unroll
            for (int i = 0; i < 4; ++i) {
                af[i]  = *(const bf16x8*)(abase[i] + off);
                bfr[i] = *(const bf16x8*)(bbase[i] + off);
            }
            #pragma unroll
            for (int i = 0; i < 4; ++i)
                #pragma unroll
                for (int j = 0; j < 4; ++j)
                    acc[i][j] = __builtin_amdgcn_mfma_f32_16x16x32_bf16(
                        af[i], bfr[j], acc[i][j], 0, 0, 0);
        }
    }

    // --- Epilogue (round-2 proven form + nt scalar stores) ---
    // C/D layout: col = lane&15, row = quad*4 + reg [m89/m91].
    #pragma unroll
    for (int i = 0; i < 4; ++i) {
        const int grow0 = bm + wm * 64 + i * 16 + quad * 4;
        float xn[4];
        #pragma unroll
        for (int r = 0; r < 4; ++r) xn[r] = x2s[grow0 + r];
        #pragma unroll
        for (int j = 0; j < 4; ++j) {
            const int gcol = bn + wn * 64 + j * 16 + l15;
            const float yn = y2s[gcol];
            #pragma unroll
            for (int r = 0; r < 4; ++r) {
                float t2 = fmaf(A2, acc[i][j][r], -(xn[r] + yn));
                t2 = fminf(t2, 0.0f);
                __builtin_nontemporal_store(
                    exp2f(t2), out + (size_t)(grow0 + r) * NC + gcol);
            }
        }
    }
}

extern "C" void kernel_launch(void* const* d_in, const int* in_sizes, int n_in,
                              void* d_out, int out_size, void* d_ws, size_t ws_size,
                              hipStream_t stream) {
    const float* x = (const float*)d_in[0];
    const float* y = (const float*)d_in[1];
    const float* gamma = (const float*)d_in[2];
    float* out = (float*)d_out;

    // Workspace layout: xb (4 MB) | yb (4 MB) | x2s (32 KB) | y2s (32 KB)
    bf16_t* xb = (bf16_t*)d_ws;
    bf16_t* yb = xb + (size_t)NB * ND;
    float*  x2s = (float*)(yb + (size_t)NC * ND);
    float*  y2s = x2s + NB;

    prep_kernel<<<dim3((NB + NC) / 4), dim3(256), 0, stream>>>(
        x, y, gamma, xb, yb, x2s, y2s);
    rbf_gemm_kernel<<<dim3(NB / BM, NC / BN), dim3(256), 0, stream>>>(
        xb, yb, x2s, y2s, gamma, out);
}

// Round 6
// 302.560 us; speedup vs baseline: 1.2506x; 1.2506x over previous
//
#include <hip/hip_runtime.h>
#include <hip/hip_bf16.h>

typedef __bf16 bf16_t;
typedef __attribute__((ext_vector_type(8))) __bf16 bf16x8;
typedef __attribute__((ext_vector_type(4))) __bf16 bf16x4;
typedef __attribute__((ext_vector_type(4))) float floatx4;

#define NB 8192   // rows of x (B)
#define NC 8192   // rows of y (C)
#define ND 256    // feature dim D
#define BM 128
#define BN 128
#define BK 32     // dbuf: 2 x (8+8) KB = 32 KB -> still 3 blocks/CU
#define LOG2E 1.44269504088896340736f

typedef __attribute__((address_space(3))) void lds_void_t;
typedef __attribute__((address_space(1))) void gl_void_t;

// ---------------------------------------------------------------------------
// prep: fp32 -> bf16 copies of x and y, plus SCALED row squared-norms:
//   x2s[r] = gamma * log2(e) * ||x_r||^2   (same for y2s)
// One wave per row (256 floats = 64 lanes x float4).
// ---------------------------------------------------------------------------
__global__ __launch_bounds__(256) void prep_kernel(
    const float* __restrict__ x, const float* __restrict__ y,
    const float* __restrict__ gamma_p,
    bf16_t* __restrict__ xb, bf16_t* __restrict__ yb,
    float* __restrict__ x2s, float* __restrict__ y2s)
{
    int t    = threadIdx.x;
    int wave = t >> 6;
    int lane = t & 63;
    int row  = blockIdx.x * 4 + wave;   // 0..16383 (x rows then y rows)

    const float* src;
    bf16_t* dst;
    float* nrm;
    int r;
    if (row < NB) { src = x; dst = xb; nrm = x2s; r = row; }
    else          { src = y; dst = yb; nrm = y2s; r = row - NB; }

    float4 v = ((const float4*)(src + (size_t)r * ND))[lane];
    float ss = v.x * v.x + v.y * v.y + v.z * v.z + v.w * v.w;

    bf16x4 o;
    o.x = (__bf16)v.x; o.y = (__bf16)v.y; o.z = (__bf16)v.z; o.w = (__bf16)v.w;
    ((bf16x4*)(dst + (size_t)r * ND))[lane] = o;

    #pragma unroll
    for (int off = 32; off >= 1; off >>= 1)
        ss += __shfl_xor(ss, off, 64);
    if (lane == 0) nrm[r] = ss * (LOG2E * gamma_p[0]);
}

// ---------------------------------------------------------------------------
// RBF GEMM: out[b,c] = 2^( min( A2*dot(x_b,y_c) - (x2s[b]+y2s[c]), 0 ) ).
// Round-2 structure (best measured: 291 us total) + T3-minimum 2-phase
// double-buffered staging (§5.5 recipe, +10% proven on grouped GEMM):
//   prologue: STAGE(buf0, kt=0); barrier
//   iter kt : STAGE(buf[cur^1], kt+1)   <- issued BEFORE compute
//             ds_read + 16 MFMA from buf[cur]
//             __syncthreads()           <- one vmcnt/lgkm drain per K-step;
//                                          loads had the whole compute phase
//                                          to land -> latency hidden
// BK=32, 8 K-iters. LDS swizzle for the 64-B row: byte ^= (row&3)<<4
// (4-way residue = 1.58x on ds_read_b128, minor). Linear LDS dest +
// pre-swizzled global source (rule #21), same XOR on the read side.
// NO XCD swizzle: inputs are L2/L3-resident (round-5 FETCH=15.5 MB), and
// swizzle costs ~2% when L3-fit (m160). Round-2's 291 had none.
// ---------------------------------------------------------------------------
__global__ __launch_bounds__(256, 3) void rbf_gemm_kernel(
    const bf16_t* __restrict__ xb, const bf16_t* __restrict__ yb,
    const float* __restrict__ x2s, const float* __restrict__ y2s,
    const float* __restrict__ gamma_p, float* __restrict__ out)
{
    __shared__ bf16_t lA[2][BM * BK];   // 2 x 8 KB
    __shared__ bf16_t lB[2][BN * BK];   // 2 x 8 KB

    const int t    = threadIdx.x;
    const int lane = t & 63;
    const int wave = t >> 6;
    const int wm   = wave >> 1;      // 2x2 wave grid over the 128x128 tile
    const int wn   = wave & 1;
    const int quad = lane >> 4;
    const int l15  = lane & 15;

    const int bm = blockIdx.x * BM;  // x-row base
    const int bn = blockIdx.y * BN;  // y-row (output col) base

    const float A2 = 2.0f * LOG2E * gamma_p[0];

    floatx4 acc[4][4];
    #pragma unroll
    for (int i = 0; i < 4; ++i)
        #pragma unroll
        for (int j = 0; j < 4; ++j)
            acc[i][j] = (floatx4){0.f, 0.f, 0.f, 0.f};

    // Staging geometry (per buffer): 8 KB = 512 x 16B chunks; thread t,
    // call c owns chunk li = c*256+t -> row = li>>2, k-byte = (li&3)*16,
    // source col XOR-swizzled by (row&3)<<4.
    const char* gA = (const char*)xb + (size_t)bm * (ND * 2);
    const char* gB = (const char*)yb + (size_t)bn * (ND * 2);

    #define STAGE(dbuf, ktile)                                                 \
        do {                                                                   \
            _Pragma("unroll")                                                  \
            for (int c = 0; c < 2; ++c) {                                      \
                const int li  = c * 256 + t;                                   \
                const int row = li >> 2;                                       \
                const int kb  = (li & 3) * 16;                                 \
                const int kbs = kb ^ ((row & 3) << 4);                         \
                const size_t goff =                                            \
                    (size_t)row * (ND * 2) + (ktile) * (BK * 2) + kbs;         \
                __builtin_amdgcn_global_load_lds(                              \
                    (gl_void_t*)(gA + goff),                                   \
                    (lds_void_t*)((char*)&lA[dbuf][0] + (size_t)li * 16),      \
                    16, 0, 0);                                                 \
                __builtin_amdgcn_global_load_lds(                              \
                    (gl_void_t*)(gB + goff),                                   \
                    (lds_void_t*)((char*)&lB[dbuf][0] + (size_t)li * 16),      \
                    16, 0, 0);                                                 \
            }                                                                  \
        } while (0)

    // Prologue: stage tile 0 into buffer 0; drain; all waves see it.
    STAGE(0, 0);
    __syncthreads();

    for (int kt = 0; kt < ND / BK; ++kt) {          // 8 iterations
        const int cur = kt & 1;
        if (kt < ND / BK - 1)
            STAGE(cur ^ 1, kt + 1);                 // prefetch next tile

        // Compute current tile: 8 ds_read_b128 + 16 MFMA.
        bf16x8 af[4], bfr[4];
        const int off = (quad * 16) ^ ((l15 & 3) << 4);  // row&3 == l15&3
        #pragma unroll
        for (int i = 0; i < 4; ++i) {
            const int ar = wm * 64 + i * 16 + l15;
            af[i]  = *(const bf16x8*)((const char*)&lA[cur][0] + ar * (BK * 2) + off);
            const int br = wn * 64 + i * 16 + l15;
            bfr[i] = *(const bf16x8*)((const char*)&lB[cur][0] + br * (BK * 2) + off);
        }
        #pragma unroll
        for (int i = 0; i < 4; ++i)
            #pragma unroll
            for (int j = 0; j < 4; ++j)
                acc[i][j] = __builtin_amdgcn_mfma_f32_16x16x32_bf16(
                    af[i], bfr[j], acc[i][j], 0, 0, 0);

        // One drain per K-step: vmcnt(0) (next tile landed — latency was
        // hidden under this tile's ds_read+MFMA) + lgkmcnt(0) (this tile's
        // reads done before next iter overwrites buf[cur]).
        __syncthreads();
    }
    #undef STAGE

    // Epilogue (round-2 proven form). C/D: col = lane&15, row = quad*4+reg.
    #pragma unroll
    for (int i = 0; i < 4; ++i) {
        const int grow0 = bm + wm * 64 + i * 16 + quad * 4;
        float xn[4];
        #pragma unroll
        for (int r = 0; r < 4; ++r) xn[r] = x2s[grow0 + r];
        #pragma unroll
        for (int j = 0; j < 4; ++j) {
            const int gcol = bn + wn * 64 + j * 16 + l15;
            const float yn = y2s[gcol];
            #pragma unroll
            for (int r = 0; r < 4; ++r) {
                float t2 = fmaf(A2, acc[i][j][r], -(xn[r] + yn));
                t2 = fminf(t2, 0.0f);
                out[(size_t)(grow0 + r) * NC + gcol] = exp2f(t2);
            }
        }
    }
}

extern "C" void kernel_launch(void* const* d_in, const int* in_sizes, int n_in,
                              void* d_out, int out_size, void* d_ws, size_t ws_size,
                              hipStream_t stream) {
    const float* x = (const float*)d_in[0];
    const float* y = (const float*)d_in[1];
    const float* gamma = (const float*)d_in[2];
    float* out = (float*)d_out;

    // Workspace layout: xb (4 MB) | yb (4 MB) | x2s (32 KB) | y2s (32 KB)
    bf16_t* xb = (bf16_t*)d_ws;
    bf16_t* yb = xb + (size_t)NB * ND;
    float*  x2s = (float*)(yb + (size_t)NC * ND);
    float*  y2s = x2s + NB;

    prep_kernel<<<dim3((NB + NC) / 4), dim3(256), 0, stream>>>(
        x, y, gamma, xb, yb, x2s, y2s);
    rbf_gemm_kernel<<<dim3(NB / BM, NC / BN), dim3(256), 0, stream>>>(
        xb, yb, x2s, y2s, gamma, out);
}